// Round 6
// baseline (650.555 us; speedup 1.0000x reference)
//
#include <hip/hip_runtime.h>
#include <hip/hip_bf16.h>

typedef __hip_bfloat16 bf16;
typedef __attribute__((ext_vector_type(4))) float f32x4;
typedef __attribute__((ext_vector_type(8))) short bs8;

#define B_  8
#define C_  512
#define N_  4096
#define CQ_ 64

#define MFMA16(a, b, c) __builtin_amdgcn_mfma_f32_16x16x32_bf16(a, b, c, 0, 0, 0)

// ---------------------------------------------------------------------------
// Fused weight cast: Wq (8192 f4) + Wk (8192 f4) + Wv (65536 f4) in one launch
// ---------------------------------------------------------------------------
__global__ __launch_bounds__(256) void cast_weights(
    const float* __restrict__ wq, const float* __restrict__ wk,
    const float* __restrict__ wv,
    bf16* __restrict__ dq, bf16* __restrict__ dk, bf16* __restrict__ dv)
{
    int i = blockIdx.x * 256 + threadIdx.x;
    const float* src;
    bf16* dst;
    int off;
    if (i < 8192)       { src = wq; dst = dq; off = i; }
    else if (i < 16384) { src = wk; dst = dk; off = i - 8192; }
    else if (i < 81920) { src = wv; dst = dv; off = i - 16384; }
    else return;
    float4 v = *(const float4*)(src + (size_t)off * 4);
    union { bf16 h[4]; uint2 u; } pk;
    pk.h[0] = __float2bfloat16(v.x);
    pk.h[1] = __float2bfloat16(v.y);
    pk.h[2] = __float2bfloat16(v.z);
    pk.h[3] = __float2bfloat16(v.w);
    *(uint2*)(dst + (size_t)off * 4) = pk.u;
}

// ---------------------------------------------------------------------------
// x [B][C][N] fp32 -> xT [B][N][C] bf16  (64c x 64n tiles via LDS)
// ---------------------------------------------------------------------------
__global__ __launch_bounds__(256) void cast_transpose(
    const float* __restrict__ x, bf16* __restrict__ xT)
{
    const int b = blockIdx.z, c0 = blockIdx.y * 64, n0 = blockIdx.x * 64;
    const int t = threadIdx.x;
    __shared__ bf16 tile[64][72];   // [n][c]

    const float* xb = x + ((size_t)b * C_ + c0) * N_ + n0;
    const int cr = t >> 4;
    const int nc4 = (t & 15) * 4;
#pragma unroll
    for (int r = 0; r < 4; r++) {
        int c = cr + r * 16;
        float4 v = *(const float4*)&xb[(size_t)c * N_ + nc4];
        tile[nc4 + 0][c] = __float2bfloat16(v.x);
        tile[nc4 + 1][c] = __float2bfloat16(v.y);
        tile[nc4 + 2][c] = __float2bfloat16(v.z);
        tile[nc4 + 3][c] = __float2bfloat16(v.w);
    }
    __syncthreads();

    bf16* dst = xT + ((size_t)b * N_ + n0) * C_ + c0;
#pragma unroll
    for (int rep = 0; rep < 2; rep++) {
        int idx = t + rep * 256;
        int row = idx >> 3, seg = idx & 7;
        *(uint4*)&dst[(size_t)row * C_ + seg * 8] = *(uint4*)&tile[row][seg * 8];
    }
}

// ---------------------------------------------------------------------------
// MFMA projection GEMM: D[o][n] = sum_c W[o][c] * xT[n][c] (+bias[o])
// MODE 0: out[n][64] bf16 (Q/K, o0==0).  MODE 1: out[o][N] bf16 (Vt).
// ---------------------------------------------------------------------------
template <int MODE>
__global__ __launch_bounds__(256, 4) void mfma_gemm(
    const bf16* __restrict__ xT, const bf16* __restrict__ Wb,
    const float* __restrict__ bias, bf16* __restrict__ out)
{
    const int b = blockIdx.z, n0 = blockIdx.x * 64, o0 = blockIdx.y * 64;
    const int t = threadIdx.x;
    const int wave = t >> 6, lane = t & 63, quad = lane >> 4, l16 = lane & 15;
    __shared__ bf16 st[64][72];

    const bf16* Arow = Wb + (size_t)(o0 + wave * 16 + l16) * C_ + quad * 8;
    const bf16* Brow = xT + ((size_t)b * N_ + n0 + l16) * C_ + quad * 8;

    f32x4 acc[4];
#pragma unroll
    for (int nc = 0; nc < 4; nc++) acc[nc] = (f32x4){0.f, 0.f, 0.f, 0.f};

    bs8 a_cur = *(const bs8*)Arow;
    bs8 b_cur[4];
#pragma unroll
    for (int nc = 0; nc < 4; nc++)
        b_cur[nc] = *(const bs8*)(Brow + (size_t)nc * 16 * C_);

#pragma unroll
    for (int c0 = 0; c0 < C_; c0 += 32) {
        bs8 a_nxt;
        bs8 b_nxt[4];
        if (c0 + 32 < C_) {
            a_nxt = *(const bs8*)(Arow + c0 + 32);
#pragma unroll
            for (int nc = 0; nc < 4; nc++)
                b_nxt[nc] = *(const bs8*)(Brow + (size_t)nc * 16 * C_ + c0 + 32);
        }
#pragma unroll
        for (int nc = 0; nc < 4; nc++)
            acc[nc] = MFMA16(a_cur, b_cur[nc], acc[nc]);
        a_cur = a_nxt;
#pragma unroll
        for (int nc = 0; nc < 4; nc++) b_cur[nc] = b_nxt[nc];
    }

    float bias_r[4];
#pragma unroll
    for (int r = 0; r < 4; r++)
        bias_r[r] = bias[o0 + wave * 16 + quad * 4 + r];

#pragma unroll
    for (int nc = 0; nc < 4; nc++)
#pragma unroll
        for (int r = 0; r < 4; r++) {
            bf16 hv = __float2bfloat16(acc[nc][r] + bias_r[r]);
            if (MODE == 0)
                st[nc * 16 + l16][wave * 16 + quad * 4 + r] = hv;
            else
                st[wave * 16 + quad * 4 + r][nc * 16 + l16] = hv;
        }
    __syncthreads();

#pragma unroll
    for (int rep = 0; rep < 2; rep++) {
        int idx = t + rep * 256;
        int row = idx >> 3, seg = idx & 7;
        uint4 v = *(uint4*)&st[row][seg * 8];
        if (MODE == 0)
            *(uint4*)&out[((size_t)b * N_ + n0 + row) * CQ_ + seg * 8] = v;
        else
            *(uint4*)&out[((size_t)b * C_ + o0 + row) * N_ + n0 + seg * 8] = v;
    }
}

// ---------------------------------------------------------------------------
// Fused attention v5: V-traffic halving via 128 i-rows per block.
//  Empirical law from R0-R5: dur = V_bytes / ~6.4 TB/s (occupancy, barriers,
//  VALU all null).  i-tile 128 amortizes each V byte over 2x Q rows ->
//  V traffic 2 GB -> 1 GB.
//  - 4 waves, channel-split 2x (blockIdx.z): 256 ch per block.
//  - Q in swizzled LDS (16 KB, staged once) -- frees ~64 VGPR for oacc[8][4].
//  - P dbuf [128 i][64 j] in LDS (2x16 KB), R4's proven 0-conflict swizzle.
//  - lgkm-only publish barrier (R4), K/V prefetch (R0), setprio.
//  - Per-element math order identical to R0/R2/R4 -> bit-identical output.
// ---------------------------------------------------------------------------
__global__ __launch_bounds__(256, 2) void attn_fused(
    const bf16* __restrict__ Qg, const bf16* __restrict__ Kg,
    const bf16* __restrict__ Vt, const float* __restrict__ x,
    const float* __restrict__ gamma, float* __restrict__ out)
{
    const int b    = blockIdx.x;          // batch -> XCD affinity
    const int i0   = blockIdx.y * 128;
    const int ch0  = blockIdx.z * 256;    // channel half
    const int t    = threadIdx.x;
    const int wave = t >> 6;
    const int lane = t & 63;
    const int quad = lane >> 4;
    const int l16  = lane & 15;

    // LDS: Q [0,16K), P0 [16K,32K), P1 [32K,48K). 128B rows, 16B-xor swizzle.
    __shared__ __align__(16) char lds[49152];
    char* ldsQ = lds;
    char* ldsP = lds + 16384;

    {   // stage Q tile (128 x 64 bf16), 64B per thread
        const int r  = t >> 1;            // 0..127
        const int b4 = (t & 1) * 4;       // 16B-block base
        const bf16* src = Qg + ((size_t)b * N_ + i0 + r) * CQ_ + b4 * 8;
#pragma unroll
        for (int k = 0; k < 4; k++) {
            uint4 v = *(const uint4*)(src + k * 8);
            *(uint4*)(ldsQ + r * 128 + (((b4 + k) ^ (r & 7)) << 4)) = v;
        }
    }

    bs8 ones;
#pragma unroll
    for (int e = 0; e < 8; e++) ones[e] = (short)0x3F80;

    f32x4 oacc[8][4];
#pragma unroll
    for (int s = 0; s < 8; s++)
#pragma unroll
        for (int c = 0; c < 4; c++) oacc[s][c] = (f32x4){0.f, 0.f, 0.f, 0.f};
    f32x4 lacc[8];
#pragma unroll
    for (int s = 0; s < 8; s++) lacc[s] = (f32x4){0.f, 0.f, 0.f, 0.f};

    const bf16* Kbase = Kg + ((size_t)b * N_ + wave * 16 + l16) * CQ_ + quad * 8;
    const bf16* Vbase = Vt + ((size_t)(b * C_ + ch0 + wave * 64 + l16)) * (size_t)N_ + quad * 8;

    bs8 kb0 = *(const bs8*)(Kbase);
    bs8 kb1 = *(const bs8*)(Kbase + 32);

    __syncthreads();   // Q staged

    for (int jt = 0; jt < 64; jt++) {
        const int j0 = jt * 64;
        const bf16* vj = Vbase + j0;

        // V working set (4 ct x 16 ch x 64 j) + next-tile K, issued up front;
        // latency hides under S + exp (and the non-draining barrier).
        bs8 vb[4][2];
#pragma unroll
        for (int p = 0; p < 4; p++) {
            vb[p][0] = *(const bs8*)(vj + (size_t)p * 16 * N_);
            vb[p][1] = *(const bs8*)(vj + (size_t)p * 16 * N_ + 32);
        }
        bs8 nk0, nk1;
        if (jt < 63) {
            nk0 = *(const bs8*)(Kbase + (size_t)(j0 + 64) * CQ_);
            nk1 = *(const bs8*)(Kbase + (size_t)(j0 + 64) * CQ_ + 32);
        }

        // S = Q.K^T rows i0..i0+127, cols j0+wave*16..+16; P=exp(S) -> LDS.
        char* pbuf = ldsP + (jt & 1) * 16384;
#pragma unroll
        for (int sub = 0; sub < 8; sub++) {
            int r = sub * 16 + l16;
            bs8 qa0 = *(const bs8*)(ldsQ + r * 128 + (((quad    ) ^ (r & 7)) << 4));
            bs8 qa1 = *(const bs8*)(ldsQ + r * 128 + (((quad + 4) ^ (r & 7)) << 4));
            f32x4 z = (f32x4){0.f, 0.f, 0.f, 0.f};
            z = MFMA16(qa0, kb0, z);
            z = MFMA16(qa1, kb1, z);
#pragma unroll
            for (int reg = 0; reg < 4; reg++) {
                int row = sub * 16 + quad * 4 + reg;
                int col = wave * 16 + l16;
                bf16 h = __float2bfloat16(__expf(z[reg]));
                *(short*)(pbuf + row * 128 +
                          ((((col >> 3) ^ (row & 7)) << 4)) + (col & 7) * 2) = *(short*)&h;
            }
        }

        // Publish P: drain LDS ops only -- global V/K loads stay in flight.
        asm volatile("s_waitcnt lgkmcnt(0)" ::: "memory");
        __builtin_amdgcn_s_barrier();
        __builtin_amdgcn_sched_barrier(0);

        // l += P.1 ; O += P.V   (8 row-subtiles x 4 ct)
        __builtin_amdgcn_s_setprio(1);
#pragma unroll
        for (int sub = 0; sub < 8; sub++) {
            int r = sub * 16 + l16;
            bs8 pa0 = *(const bs8*)(pbuf + r * 128 + (((quad    ) ^ (r & 7)) << 4));
            bs8 pa1 = *(const bs8*)(pbuf + r * 128 + (((quad + 4) ^ (r & 7)) << 4));
            lacc[sub] = MFMA16(pa0, ones, lacc[sub]);
            lacc[sub] = MFMA16(pa1, ones, lacc[sub]);
#pragma unroll
            for (int ct = 0; ct < 4; ct++) {
                oacc[sub][ct] = MFMA16(pa0, vb[ct][0], oacc[sub][ct]);
                oacc[sub][ct] = MFMA16(pa1, vb[ct][1], oacc[sub][ct]);
            }
        }
        __builtin_amdgcn_s_setprio(0);

        kb0 = nk0; kb1 = nk1;
    }

    // ---- epilogue: out = gamma*O/l + x ----
    const float g = gamma[0];
#pragma unroll
    for (int sub = 0; sub < 8; sub++) {
        float inv0 = g / lacc[sub][0];
        float inv1 = g / lacc[sub][1];
        float inv2 = g / lacc[sub][2];
        float inv3 = g / lacc[sub][3];
#pragma unroll
        for (int ct = 0; ct < 4; ct++) {
            int c = ch0 + wave * 64 + ct * 16 + l16;
            int n = i0 + sub * 16 + quad * 4;
            size_t idx = ((size_t)b * C_ + c) * N_ + n;
            float4 xv = *(const float4*)(x + idx);
            float4 o;
            o.x = oacc[sub][ct][0] * inv0 + xv.x;
            o.y = oacc[sub][ct][1] * inv1 + xv.y;
            o.z = oacc[sub][ct][2] * inv2 + xv.z;
            o.w = oacc[sub][ct][3] * inv3 + xv.w;
            *(float4*)(out + idx) = o;
        }
    }
}

// ---------------------------------------------------------------------------
extern "C" void kernel_launch(void* const* d_in, const int* in_sizes, int n_in,
                              void* d_out, int out_size, void* d_ws, size_t ws_size,
                              hipStream_t stream)
{
    const float* x     = (const float*)d_in[0];
    const float* Wq    = (const float*)d_in[1];
    const float* bq    = (const float*)d_in[2];
    const float* Wk    = (const float*)d_in[3];
    const float* bk    = (const float*)d_in[4];
    const float* Wv    = (const float*)d_in[5];
    const float* bv    = (const float*)d_in[6];
    const float* gamma = (const float*)d_in[7];
    float* out = (float*)d_out;

    dim3 blk(256);

    const size_t szXT = (size_t)B_ * N_ * C_ * sizeof(bf16);   // 33,554,432
    const size_t szQ  = (size_t)B_ * N_ * CQ_ * sizeof(bf16);  //  4,194,304
    const size_t szVt = szXT;                                  // 33,554,432
    const size_t szWq = (size_t)CQ_ * C_ * sizeof(bf16);       //     65,536
    const size_t szWv = (size_t)C_ * C_ * sizeof(bf16);        //    524,288
    const size_t need_full = szXT + 2 * szQ + szVt + 2 * szWq + szWv; // ~72.6 MB

    if (ws_size >= need_full) {
        char* ws = (char*)d_ws;
        bf16* xT  = (bf16*)ws;
        bf16* Q   = (bf16*)(ws + szXT);
        bf16* K   = (bf16*)(ws + szXT + szQ);
        bf16* Vt  = (bf16*)(ws + szXT + 2 * szQ);
        bf16* Wqb = (bf16*)(ws + szXT + 2 * szQ + szVt);
        bf16* Wkb = (bf16*)((char*)Wqb + szWq);
        bf16* Wvb = (bf16*)((char*)Wkb + szWq);

        cast_weights<<<dim3(320), blk, 0, stream>>>(Wq, Wk, Wv, Wqb, Wkb, Wvb);
        cast_transpose<<<dim3(64, 8, B_), blk, 0, stream>>>(x, xT);

        mfma_gemm<0><<<dim3(64, 1, B_), blk, 0, stream>>>(xT, Wqb, bq, Q);
        mfma_gemm<0><<<dim3(64, 1, B_), blk, 0, stream>>>(xT, Wkb, bk, K);
        mfma_gemm<1><<<dim3(64, 8, B_), blk, 0, stream>>>(xT, Wvb, bv, Vt);

        attn_fused<<<dim3(B_, 32, 2), blk, 0, stream>>>(Q, K, Vt, x, gamma, out);
    } else {
        // Per-batch chunked fallback
        const size_t xtb = (size_t)N_ * C_ * sizeof(bf16);
        const size_t qb  = (size_t)N_ * CQ_ * sizeof(bf16);
        char* ws = (char*)d_ws;
        bf16* Wqb = (bf16*)ws;
        bf16* Wkb = (bf16*)(ws + szWq);
        bf16* Wvb = (bf16*)(ws + 2 * szWq);
        bf16* xT  = (bf16*)(ws + 2 * szWq + szWv);
        bf16* Q   = (bf16*)((char*)xT + xtb);
        bf16* K   = (bf16*)((char*)Q + qb);
        bf16* Vt  = (bf16*)((char*)K + qb);

        cast_weights<<<dim3(320), blk, 0, stream>>>(Wq, Wk, Wv, Wqb, Wkb, Wvb);

        for (int b = 0; b < B_; b++) {
            const float* xb = x + (size_t)b * C_ * N_;
            float*       ob = out + (size_t)b * C_ * N_;
            cast_transpose<<<dim3(64, 8, 1), blk, 0, stream>>>(xb, xT);
            mfma_gemm<0><<<dim3(64, 1, 1), blk, 0, stream>>>(xT, Wqb, bq, Q);
            mfma_gemm<0><<<dim3(64, 1, 1), blk, 0, stream>>>(xT, Wkb, bk, K);
            mfma_gemm<1><<<dim3(64, 8, 1), blk, 0, stream>>>(xT, Wvb, bv, Vt);
            attn_fused<<<dim3(1, 32, 2), blk, 0, stream>>>(Q, K, Vt, xb, gamma, ob);
        }
    }
}

// Round 7
// 497.813 us; speedup vs baseline: 1.3068x; 1.3068x over previous
//
#include <hip/hip_runtime.h>
#include <hip/hip_bf16.h>

typedef __hip_bfloat16 bf16;
typedef __attribute__((ext_vector_type(4))) float f32x4;
typedef __attribute__((ext_vector_type(8))) short bs8;

#define B_  8
#define C_  512
#define N_  4096
#define CQ_ 64

#define MFMA16(a, b, c) __builtin_amdgcn_mfma_f32_16x16x32_bf16(a, b, c, 0, 0, 0)

// ---------------------------------------------------------------------------
// Fused weight cast: Wq (8192 f4) + Wk (8192 f4) + Wv (65536 f4) in one launch
// ---------------------------------------------------------------------------
__global__ __launch_bounds__(256) void cast_weights(
    const float* __restrict__ wq, const float* __restrict__ wk,
    const float* __restrict__ wv,
    bf16* __restrict__ dq, bf16* __restrict__ dk, bf16* __restrict__ dv)
{
    int i = blockIdx.x * 256 + threadIdx.x;
    const float* src;
    bf16* dst;
    int off;
    if (i < 8192)       { src = wq; dst = dq; off = i; }
    else if (i < 16384) { src = wk; dst = dk; off = i - 8192; }
    else if (i < 81920) { src = wv; dst = dv; off = i - 16384; }
    else return;
    float4 v = *(const float4*)(src + (size_t)off * 4);
    union { bf16 h[4]; uint2 u; } pk;
    pk.h[0] = __float2bfloat16(v.x);
    pk.h[1] = __float2bfloat16(v.y);
    pk.h[2] = __float2bfloat16(v.z);
    pk.h[3] = __float2bfloat16(v.w);
    *(uint2*)(dst + (size_t)off * 4) = pk.u;
}

// ---------------------------------------------------------------------------
// Fused projection: per (64-n tile, batch) block,
//   stage x[b][:, n0..n0+63] -> LDS xs[n][c] bf16 (XOR-swizzled 16B blocks),
//   then 10 o-tiles (Q:1, K:1, V:8): D[o][n] = sum_c W[o][c]*x[c][n] + bias.
// Replaces cast_transpose + 3 mfma_gemm launches + the xT intermediate.
// Accumulation order / rounding identical to the old mfma_gemm -> outputs
// are bit-identical.
// ---------------------------------------------------------------------------
__device__ __forceinline__ bs8 xs_read(const char* xs, int l16, int quad,
                                       int nc, int c0)
{
    return *(const bs8*)(xs + (nc * 16 + l16) * 1024 +
                         (((((c0) >> 3) + quad) ^ (l16 & 7)) << 4));
}

__global__ __launch_bounds__(256, 2) void proj_fused(
    const float* __restrict__ x,
    const bf16* __restrict__ Wqb, const bf16* __restrict__ Wkb,
    const bf16* __restrict__ Wvb,
    const float* __restrict__ bq, const float* __restrict__ bk,
    const float* __restrict__ bv,
    bf16* __restrict__ Qo, bf16* __restrict__ Ko, bf16* __restrict__ Vt)
{
    const int b  = blockIdx.y;
    const int n0 = blockIdx.x * 64;
    const int t  = threadIdx.x;
    const int wave = t >> 6, lane = t & 63, quad = lane >> 4, l16 = lane & 15;

    // xs[n][c]: 64 rows of 1024 B; 16B block index (c>>3) XOR'd with (n&7).
    __shared__ __align__(16) char xs[65536];

    {   // stage: thread covers n = n2,n2+1 and 4 consecutive c per r-step
        const int n2 = (t & 31) * 2;
        const int cw = t >> 5;            // 0..7
#pragma unroll
        for (int r = 0; r < 16; r++) {
            const int c0r = cw * 4 + r * 32;
            float2 v0 = *(const float2*)&x[((size_t)b * C_ + c0r + 0) * N_ + n0 + n2];
            float2 v1 = *(const float2*)&x[((size_t)b * C_ + c0r + 1) * N_ + n0 + n2];
            float2 v2 = *(const float2*)&x[((size_t)b * C_ + c0r + 2) * N_ + n0 + n2];
            float2 v3 = *(const float2*)&x[((size_t)b * C_ + c0r + 3) * N_ + n0 + n2];
            const int blkh = ((c0r >> 3) << 4) | ((c0r & 4) << 1); // blk*16+half*8
            {
                union { bf16 h[4]; uint2 u; } pk;
                pk.h[0] = __float2bfloat16(v0.x);
                pk.h[1] = __float2bfloat16(v1.x);
                pk.h[2] = __float2bfloat16(v2.x);
                pk.h[3] = __float2bfloat16(v3.x);
                const int n = n2;
                *(uint2*)(xs + n * 1024 + (blkh ^ ((n & 7) << 4))) = pk.u;
            }
            {
                union { bf16 h[4]; uint2 u; } pk;
                pk.h[0] = __float2bfloat16(v0.y);
                pk.h[1] = __float2bfloat16(v1.y);
                pk.h[2] = __float2bfloat16(v2.y);
                pk.h[3] = __float2bfloat16(v3.y);
                const int n = n2 + 1;
                *(uint2*)(xs + n * 1024 + (blkh ^ ((n & 7) << 4))) = pk.u;
            }
        }
    }
    __syncthreads();

    for (int ot = 0; ot < 10; ot++) {
        const bf16* Wb;
        const float* bias;
        int obase;
        if (ot == 0)      { Wb = Wqb; bias = bq; obase = 0; }
        else if (ot == 1) { Wb = Wkb; bias = bk; obase = 0; }
        else              { Wb = Wvb; bias = bv; obase = (ot - 2) * 64; }

        const bf16* Arow = Wb + (size_t)(obase + wave * 16 + l16) * C_ + quad * 8;

        f32x4 acc[4];
#pragma unroll
        for (int nc = 0; nc < 4; nc++) acc[nc] = (f32x4){0.f, 0.f, 0.f, 0.f};

        bs8 a0 = *(const bs8*)(Arow);
        bs8 a1 = *(const bs8*)(Arow + 32);
        bs8 b_cur[4];
#pragma unroll
        for (int nc = 0; nc < 4; nc++) b_cur[nc] = xs_read(xs, l16, quad, nc, 0);

#pragma unroll
        for (int c0 = 0; c0 < C_; c0 += 32) {
            bs8 a2;
            bs8 b_nxt[4];
            if (c0 + 64 < C_) a2 = *(const bs8*)(Arow + c0 + 64);
            if (c0 + 32 < C_) {
#pragma unroll
                for (int nc = 0; nc < 4; nc++)
                    b_nxt[nc] = xs_read(xs, l16, quad, nc, c0 + 32);
            }
#pragma unroll
            for (int nc = 0; nc < 4; nc++)
                acc[nc] = MFMA16(a0, b_cur[nc], acc[nc]);
            a0 = a1; a1 = a2;
#pragma unroll
            for (int nc = 0; nc < 4; nc++) b_cur[nc] = b_nxt[nc];
        }

        float bias_r[4];
#pragma unroll
        for (int r = 0; r < 4; r++)
            bias_r[r] = bias[obase + wave * 16 + quad * 4 + r];

        if (ot < 2) {
            bf16* dst = (ot == 0) ? Qo : Ko;
#pragma unroll
            for (int nc = 0; nc < 4; nc++)
#pragma unroll
                for (int r = 0; r < 4; r++) {
                    bf16 hv = __float2bfloat16(acc[nc][r] + bias_r[r]);
                    dst[((size_t)b * N_ + n0 + nc * 16 + l16) * CQ_ +
                        wave * 16 + quad * 4 + r] = hv;
                }
        } else {
#pragma unroll
            for (int nc = 0; nc < 4; nc++)
#pragma unroll
                for (int r = 0; r < 4; r++) {
                    bf16 hv = __float2bfloat16(acc[nc][r] + bias_r[r]);
                    Vt[((size_t)b * C_ + obase + wave * 16 + quad * 4 + r) * (size_t)N_ +
                       n0 + nc * 16 + l16] = hv;
                }
        }
    }
}

// ---------------------------------------------------------------------------
// Fused attention (R5 kernel, verbatim — measured 336.5 us):
//  - 64 i-rows, 4 waves, channel-split 2x (blockIdx.z), 2 blocks/CU.
//  - KVBLK=128 (32 iterations), P dbuf XOR-swizzled, zero per-access VALU.
//  - lgkm-only publish barrier; K/V incremental pointers.
// ---------------------------------------------------------------------------
__global__ __launch_bounds__(256, 2) void attn_fused(
    const bf16* __restrict__ Qg, const bf16* __restrict__ Kg,
    const bf16* __restrict__ Vt, const float* __restrict__ x,
    const float* __restrict__ gamma, float* __restrict__ out)
{
    const int b    = blockIdx.x;          // batch -> XCD affinity
    const int i0   = blockIdx.y * 64;
    const int ch0  = blockIdx.z * 256;    // channel half
    const int t    = threadIdx.x;
    const int wave = t >> 6;
    const int lane = t & 63;
    const int quad = lane >> 4;
    const int l16  = lane & 15;

    __shared__ __align__(16) char lds[32768];   // P double buffer

    bs8 qa0[4], qa1[4];
#pragma unroll
    for (int sub = 0; sub < 4; sub++) {
        const bf16* q = Qg + ((size_t)b * N_ + i0 + sub * 16 + l16) * CQ_ + quad * 8;
        qa0[sub] = *(const bs8*)(q);
        qa1[sub] = *(const bs8*)(q + 32);
    }

    bs8 ones;
#pragma unroll
    for (int e = 0; e < 8; e++) ones[e] = (short)0x3F80;

    f32x4 oacc[4][4];
#pragma unroll
    for (int s = 0; s < 4; s++)
#pragma unroll
        for (int c = 0; c < 4; c++) oacc[s][c] = (f32x4){0.f, 0.f, 0.f, 0.f};
    f32x4 lacc[4];
#pragma unroll
    for (int s = 0; s < 4; s++) lacc[s] = (f32x4){0.f, 0.f, 0.f, 0.f};

    const int l7  = l16 & 7;
    const int lh  = l16 >> 3;
    const int lb2 = (l16 >> 2) & 1;
    const int l3  = l16 & 3;
    const int wbase = quad * 1024 + (((wave & 1) ^ (quad & 1)) << 6) +
                      ((wave >> 1) << 7) + (lh << 4) + l7 * 2;
    int awr[4];
#pragma unroll
    for (int c = 0; c < 4; c++) awr[c] = wbase ^ (c << 4);
    const int rbase = l16 * 256 + ((quad ^ l3) << 4) + (lb2 << 6);
    int ard[2];
    ard[0] = rbase;
    ard[1] = rbase ^ 64;

    const bf16* Kp = Kg + ((size_t)b * N_ + wave * 32 + l16) * CQ_ + quad * 8;
    const bf16* Vp[4];
#pragma unroll
    for (int ct = 0; ct < 4; ct++)
        Vp[ct] = Vt + ((size_t)(b * C_ + ch0 + wave * 64 + ct * 16 + l16)) * (size_t)N_
                 + quad * 8;

    for (int jt = 0; jt < 32; jt++) {
        bs8 kb[2][2];
#pragma unroll
        for (int cs = 0; cs < 2; cs++)
#pragma unroll
            for (int kh = 0; kh < 2; kh++)
                kb[cs][kh] = *(const bs8*)(Kp + cs * 1024 + kh * 32);

        bs8 vbA[4][2];
#pragma unroll
        for (int ct = 0; ct < 4; ct++)
#pragma unroll
            for (int kc = 0; kc < 2; kc++)
                vbA[ct][kc] = *(const bs8*)(Vp[ct] + kc * 32);

#pragma unroll
        for (int cs = 0; cs < 2; cs++) {
            f32x4 sacc[4];
#pragma unroll
            for (int sub = 0; sub < 4; sub++) {
                f32x4 z = (f32x4){0.f, 0.f, 0.f, 0.f};
                z = MFMA16(qa0[sub], kb[cs][0], z);
                z = MFMA16(qa1[sub], kb[cs][1], z);
                sacc[sub] = z;
            }
#pragma unroll
            for (int sub = 0; sub < 4; sub++)
#pragma unroll
                for (int reg = 0; reg < 4; reg++) {
                    bf16 h = __float2bfloat16(__expf(sacc[sub][reg]));
                    const int c = ((cs ^ (reg >> 1)) << 1) | (reg & 1);
                    *(short*)(lds + awr[c] + sub * 4096 + reg * 256) = *(short*)&h;
                }
        }

        asm volatile("s_waitcnt lgkmcnt(0)" ::: "memory");
        __builtin_amdgcn_s_barrier();
        __builtin_amdgcn_sched_barrier(0);

        bs8 vbB[4][2];
#pragma unroll
        for (int kc = 0; kc < 4; kc++) {
            if (kc < 2) {
#pragma unroll
                for (int ct = 0; ct < 4; ct++)
                    vbB[ct][kc] = *(const bs8*)(Vp[ct] + (kc + 2) * 32);
            }
            bs8 pa[4];
#pragma unroll
            for (int sub = 0; sub < 4; sub++)
                pa[sub] = *(const bs8*)(lds + ard[kc & 1] + sub * 4096 + (kc >> 1) * 128);

            __builtin_amdgcn_s_setprio(1);
#pragma unroll
            for (int sub = 0; sub < 4; sub++)
                lacc[sub] = MFMA16(pa[sub], ones, lacc[sub]);
#pragma unroll
            for (int ct = 0; ct < 4; ct++) {
                bs8 v = (kc < 2) ? vbA[ct][kc] : vbB[ct][kc - 2];
#pragma unroll
                for (int sub = 0; sub < 4; sub++)
                    oacc[sub][ct] = MFMA16(pa[sub], v, oacc[sub][ct]);
            }
            __builtin_amdgcn_s_setprio(0);
        }

        Kp += 128 * CQ_;
#pragma unroll
        for (int ct = 0; ct < 4; ct++) Vp[ct] += 128;
#pragma unroll
        for (int c = 0; c < 4; c++) awr[c] ^= 16384;
        ard[0] ^= 16384;
        ard[1] ^= 16384;
    }

    const float g = gamma[0];
#pragma unroll
    for (int sub = 0; sub < 4; sub++) {
        float inv0 = g / lacc[sub][0];
        float inv1 = g / lacc[sub][1];
        float inv2 = g / lacc[sub][2];
        float inv3 = g / lacc[sub][3];
#pragma unroll
        for (int ct = 0; ct < 4; ct++) {
            int c = ch0 + wave * 64 + ct * 16 + l16;
            int n = i0 + sub * 16 + quad * 4;
            size_t idx = ((size_t)b * C_ + c) * N_ + n;
            float4 xv = *(const float4*)(x + idx);
            float4 o;
            o.x = oacc[sub][ct][0] * inv0 + xv.x;
            o.y = oacc[sub][ct][1] * inv1 + xv.y;
            o.z = oacc[sub][ct][2] * inv2 + xv.z;
            o.w = oacc[sub][ct][3] * inv3 + xv.w;
            *(float4*)(out + idx) = o;
        }
    }
}

// ---------------------------------------------------------------------------
extern "C" void kernel_launch(void* const* d_in, const int* in_sizes, int n_in,
                              void* d_out, int out_size, void* d_ws, size_t ws_size,
                              hipStream_t stream)
{
    const float* x     = (const float*)d_in[0];
    const float* Wq    = (const float*)d_in[1];
    const float* bq    = (const float*)d_in[2];
    const float* Wk    = (const float*)d_in[3];
    const float* bk    = (const float*)d_in[4];
    const float* Wv    = (const float*)d_in[5];
    const float* bv    = (const float*)d_in[6];
    const float* gamma = (const float*)d_in[7];
    float* out = (float*)d_out;

    dim3 blk(256);

    const size_t szQ  = (size_t)B_ * N_ * CQ_ * sizeof(bf16);  //  4,194,304
    const size_t szVt = (size_t)B_ * N_ * C_ * sizeof(bf16);   // 33,554,432
    const size_t szWq = (size_t)CQ_ * C_ * sizeof(bf16);       //     65,536
    const size_t szWv = (size_t)C_ * C_ * sizeof(bf16);        //    524,288
    const size_t need_full = 2 * szQ + szVt + 2 * szWq + szWv; // ~42.6 MB

    if (ws_size >= need_full) {
        char* ws = (char*)d_ws;
        bf16* Q   = (bf16*)ws;
        bf16* K   = (bf16*)(ws + szQ);
        bf16* Vt  = (bf16*)(ws + 2 * szQ);
        bf16* Wqb = (bf16*)(ws + 2 * szQ + szVt);
        bf16* Wkb = (bf16*)((char*)Wqb + szWq);
        bf16* Wvb = (bf16*)((char*)Wkb + szWq);

        cast_weights<<<dim3(320), blk, 0, stream>>>(Wq, Wk, Wv, Wqb, Wkb, Wvb);
        proj_fused<<<dim3(64, B_), blk, 0, stream>>>(
            x, Wqb, Wkb, Wvb, bq, bk, bv, Q, K, Vt);
        attn_fused<<<dim3(B_, 64, 2), blk, 0, stream>>>(Q, K, Vt, x, gamma, out);
    } else {
        // Per-batch chunked fallback: weights + Q_b/K_b/Vt_b ~= 5.9 MB
        const size_t qb  = (size_t)N_ * CQ_ * sizeof(bf16);
        const size_t vtb = (size_t)C_ * N_ * sizeof(bf16);
        char* ws = (char*)d_ws;
        bf16* Wqb = (bf16*)ws;
        bf16* Wkb = (bf16*)(ws + szWq);
        bf16* Wvb = (bf16*)(ws + 2 * szWq);
        bf16* Q   = (bf16*)(ws + 2 * szWq + szWv);
        bf16* K   = (bf16*)((char*)Q + qb);
        bf16* Vt  = (bf16*)((char*)K + qb);

        cast_weights<<<dim3(320), blk, 0, stream>>>(Wq, Wk, Wv, Wqb, Wkb, Wvb);

        for (int b = 0; b < B_; b++) {
            const float* xb = x + (size_t)b * C_ * N_;
            float*       ob = out + (size_t)b * C_ * N_;
            proj_fused<<<dim3(64, 1), blk, 0, stream>>>(
                xb, Wqb, Wkb, Wvb, bq, bk, bv, Q, K, Vt);
            attn_fused<<<dim3(1, 64, 2), blk, 0, stream>>>(Q, K, Vt, xb, gamma, ob);
        }
    }
}

// Round 8
// 387.221 us; speedup vs baseline: 1.6801x; 1.2856x over previous
//
#include <hip/hip_runtime.h>
#include <hip/hip_bf16.h>

typedef __hip_bfloat16 bf16;
typedef __attribute__((ext_vector_type(4))) float f32x4;
typedef __attribute__((ext_vector_type(8))) short bs8;

#define B_  8
#define C_  512
#define N_  4096
#define CQ_ 64

#define MFMA16(a, b, c) __builtin_amdgcn_mfma_f32_16x16x32_bf16(a, b, c, 0, 0, 0)

// ---------------------------------------------------------------------------
// Fused weight cast: Wq (8192 f4) + Wk (8192 f4) + Wv (65536 f4) in one launch
// ---------------------------------------------------------------------------
__global__ __launch_bounds__(256) void cast_weights(
    const float* __restrict__ wq, const float* __restrict__ wk,
    const float* __restrict__ wv,
    bf16* __restrict__ dq, bf16* __restrict__ dk, bf16* __restrict__ dv)
{
    int i = blockIdx.x * 256 + threadIdx.x;
    const float* src;
    bf16* dst;
    int off;
    if (i < 8192)       { src = wq; dst = dq; off = i; }
    else if (i < 16384) { src = wk; dst = dk; off = i - 8192; }
    else if (i < 81920) { src = wv; dst = dv; off = i - 16384; }
    else return;
    float4 v = *(const float4*)(src + (size_t)off * 4);
    union { bf16 h[4]; uint2 u; } pk;
    pk.h[0] = __float2bfloat16(v.x);
    pk.h[1] = __float2bfloat16(v.y);
    pk.h[2] = __float2bfloat16(v.z);
    pk.h[3] = __float2bfloat16(v.w);
    *(uint2*)(dst + (size_t)off * 4) = pk.u;
}

// ---------------------------------------------------------------------------
// Fused projection (proven R7): per (64-n tile, batch) block, stage
// x[b][:, n0..n0+63] -> LDS, then 10 o-tiles (Q, K, 8xV).
// ---------------------------------------------------------------------------
__device__ __forceinline__ bs8 xs_read(const char* xs, int l16, int quad,
                                       int nc, int c0)
{
    return *(const bs8*)(xs + (nc * 16 + l16) * 1024 +
                         (((((c0) >> 3) + quad) ^ (l16 & 7)) << 4));
}

__global__ __launch_bounds__(256, 2) void proj_fused(
    const float* __restrict__ x,
    const bf16* __restrict__ Wqb, const bf16* __restrict__ Wkb,
    const bf16* __restrict__ Wvb,
    const float* __restrict__ bq, const float* __restrict__ bk,
    const float* __restrict__ bv,
    bf16* __restrict__ Qo, bf16* __restrict__ Ko, bf16* __restrict__ Vt)
{
    const int b  = blockIdx.y;
    const int n0 = blockIdx.x * 64;
    const int t  = threadIdx.x;
    const int wave = t >> 6, lane = t & 63, quad = lane >> 4, l16 = lane & 15;

    __shared__ __align__(16) char xs[65536];

    {
        const int n2 = (t & 31) * 2;
        const int cw = t >> 5;
#pragma unroll
        for (int r = 0; r < 16; r++) {
            const int c0r = cw * 4 + r * 32;
            float2 v0 = *(const float2*)&x[((size_t)b * C_ + c0r + 0) * N_ + n0 + n2];
            float2 v1 = *(const float2*)&x[((size_t)b * C_ + c0r + 1) * N_ + n0 + n2];
            float2 v2 = *(const float2*)&x[((size_t)b * C_ + c0r + 2) * N_ + n0 + n2];
            float2 v3 = *(const float2*)&x[((size_t)b * C_ + c0r + 3) * N_ + n0 + n2];
            const int blkh = ((c0r >> 3) << 4) | ((c0r & 4) << 1);
            {
                union { bf16 h[4]; uint2 u; } pk;
                pk.h[0] = __float2bfloat16(v0.x);
                pk.h[1] = __float2bfloat16(v1.x);
                pk.h[2] = __float2bfloat16(v2.x);
                pk.h[3] = __float2bfloat16(v3.x);
                const int n = n2;
                *(uint2*)(xs + n * 1024 + (blkh ^ ((n & 7) << 4))) = pk.u;
            }
            {
                union { bf16 h[4]; uint2 u; } pk;
                pk.h[0] = __float2bfloat16(v0.y);
                pk.h[1] = __float2bfloat16(v1.y);
                pk.h[2] = __float2bfloat16(v2.y);
                pk.h[3] = __float2bfloat16(v3.y);
                const int n = n2 + 1;
                *(uint2*)(xs + n * 1024 + (blkh ^ ((n & 7) << 4))) = pk.u;
            }
        }
    }
    __syncthreads();

    for (int ot = 0; ot < 10; ot++) {
        const bf16* Wb;
        const float* bias;
        int obase;
        if (ot == 0)      { Wb = Wqb; bias = bq; obase = 0; }
        else if (ot == 1) { Wb = Wkb; bias = bk; obase = 0; }
        else              { Wb = Wvb; bias = bv; obase = (ot - 2) * 64; }

        const bf16* Arow = Wb + (size_t)(obase + wave * 16 + l16) * C_ + quad * 8;

        f32x4 acc[4];
#pragma unroll
        for (int nc = 0; nc < 4; nc++) acc[nc] = (f32x4){0.f, 0.f, 0.f, 0.f};

        bs8 a0 = *(const bs8*)(Arow);
        bs8 a1 = *(const bs8*)(Arow + 32);
        bs8 b_cur[4];
#pragma unroll
        for (int nc = 0; nc < 4; nc++) b_cur[nc] = xs_read(xs, l16, quad, nc, 0);

#pragma unroll
        for (int c0 = 0; c0 < C_; c0 += 32) {
            bs8 a2;
            bs8 b_nxt[4];
            if (c0 + 64 < C_) a2 = *(const bs8*)(Arow + c0 + 64);
            if (c0 + 32 < C_) {
#pragma unroll
                for (int nc = 0; nc < 4; nc++)
                    b_nxt[nc] = xs_read(xs, l16, quad, nc, c0 + 32);
            }
#pragma unroll
            for (int nc = 0; nc < 4; nc++)
                acc[nc] = MFMA16(a0, b_cur[nc], acc[nc]);
            a0 = a1; a1 = a2;
#pragma unroll
            for (int nc = 0; nc < 4; nc++) b_cur[nc] = b_nxt[nc];
        }

        float bias_r[4];
#pragma unroll
        for (int r = 0; r < 4; r++)
            bias_r[r] = bias[obase + wave * 16 + quad * 4 + r];

        if (ot < 2) {
            bf16* dst = (ot == 0) ? Qo : Ko;
#pragma unroll
            for (int nc = 0; nc < 4; nc++)
#pragma unroll
                for (int r = 0; r < 4; r++) {
                    bf16 hv = __float2bfloat16(acc[nc][r] + bias_r[r]);
                    dst[((size_t)b * N_ + n0 + nc * 16 + l16) * CQ_ +
                        wave * 16 + quad * 4 + r] = hv;
                }
        } else {
#pragma unroll
            for (int nc = 0; nc < 4; nc++)
#pragma unroll
                for (int r = 0; r < 4; r++) {
                    bf16 hv = __float2bfloat16(acc[nc][r] + bias_r[r]);
                    Vt[((size_t)b * C_ + obase + wave * 16 + quad * 4 + r) * (size_t)N_ +
                       n0 + nc * 16 + l16] = hv;
                }
        }
    }
}

// ---------------------------------------------------------------------------
// Fused attention v6: V-traffic quartering via LDS-shared V/K.
//  Block = 256 i x 256 ch (z-split 2), 512 threads / 8 waves, KVBLK=64.
//  V_total: 2 GB -> 512 MB (the R0-R7 measurements show attn time ==
//  V bytes / ~6.2 TB/s; occupancy/barriers/VALU all proven null).
//  - S: wave w computes rows [w*32, w*32+32) x all 64 j (no dup exp).
//  - P [256i][64j] in LDS (32 KB, single buffer), proven XOR swizzle.
//  - K tile [64j][64c] dbuf 2x8 KB; V tile [256ch][64j] dbuf 2x32 KB.
//  - ONE lgkm-only barrier/iter: K-stage writes PRE-barrier, V-stage
//    writes POST-PV; with dbuf parity every cross-wave read/write pair of
//    the same buffer is separated by a barrier (audited per-wave).
//  - PV: wave = (iw = w>>1: 64 i) x (cw = w&1: 128 ch); P + V from LDS.
//  - Global loads for jt+1 issue at iteration top (~full iter of cover).
//  - Per-element math order identical to R5/R7 -> bit-identical output.
// ---------------------------------------------------------------------------
__global__ __launch_bounds__(512, 2) void attn_fused(
    const bf16* __restrict__ Qg, const bf16* __restrict__ Kg,
    const bf16* __restrict__ Vt, const float* __restrict__ x,
    const float* __restrict__ gamma, float* __restrict__ out)
{
    const int b    = blockIdx.x;          // batch -> XCD affinity
    const int i0   = blockIdx.y * 256;
    const int ch0  = blockIdx.z * 256;    // channel half
    const int t    = threadIdx.x;
    const int w    = t >> 6;              // 0..7
    const int lane = t & 63;
    const int quad = lane >> 4;
    const int l16  = lane & 15;
    const int l7   = l16 & 7;
    const int iw   = w >> 1;              // PV i-quarter (64 rows)
    const int cw   = w & 1;               // PV ch-half (128 ch)

    // LDS: P [0,32K) | K dbuf [32K, 48K) | V dbuf [48K, 112K)
    __shared__ __align__(16) char lds[114688];

    // ---- Q frags (wave's S rows), loaded once ----
    bs8 qa[2][2];
#pragma unroll
    for (int sub = 0; sub < 2; sub++) {
        const bf16* q = Qg + ((size_t)b * N_ + i0 + w * 32 + sub * 16 + l16) * CQ_ +
                        quad * 8;
        qa[sub][0] = *(const bs8*)(q);
        qa[sub][1] = *(const bs8*)(q + 32);
    }

    bs8 ones;
#pragma unroll
    for (int e = 0; e < 8; e++) ones[e] = (short)0x3F80;

    f32x4 oacc[4][8];
#pragma unroll
    for (int s = 0; s < 4; s++)
#pragma unroll
        for (int c = 0; c < 8; c++) oacc[s][c] = (f32x4){0.f, 0.f, 0.f, 0.f};
    f32x4 lacc[4];
#pragma unroll
    for (int s = 0; s < 4; s++) lacc[s] = (f32x4){0.f, 0.f, 0.f, 0.f};

    // ---- staging geometry ----
    const int krow = t >> 3, kblk = t & 7;          // K: 64 rows x 128B
    const int vch  = t >> 1, vhalf = t & 1;         // V: 256 rows x 128B
    const bf16* Kp = Kg + ((size_t)b * N_ + krow) * CQ_ + kblk * 8;
    const bf16* Vp = Vt + ((size_t)(b * C_ + ch0 + vch)) * (size_t)N_ + vhalf * 32;
    const int kw_off = krow * 128 + ((kblk ^ (krow & 7)) << 4);
    const int vw_row = vch * 128;
    const int vch7   = vch & 7;

    // ---- prologue: stage tile 0 into buffer 0 ----
    {
        uint4 k0 = *(const uint4*)Kp;
        *(uint4*)(lds + 32768 + kw_off) = k0;
        uint4 v0[4];
#pragma unroll
        for (int q = 0; q < 4; q++) v0[q] = *(const uint4*)(Vp + q * 8);
#pragma unroll
        for (int q = 0; q < 4; q++)
            *(uint4*)(lds + 49152 + vw_row + (((vhalf * 4 + q) ^ vch7) << 4)) = v0[q];
    }
    __syncthreads();

    for (int jt = 0; jt < 64; jt++) {
        const int cur = jt & 1, nxt = cur ^ 1;

        // ---- issue next-tile global loads (cover: full iteration) ----
        uint4 kreg;
        uint4 vreg[4];
        if (jt < 63) {
            kreg = *(const uint4*)(Kp + (size_t)(jt + 1) * 64 * CQ_);
#pragma unroll
            for (int q = 0; q < 4; q++)
                vreg[q] = *(const uint4*)(Vp + (size_t)(jt + 1) * 64 + q * 8);
        }

        // ---- S = Q.K^T (wave's 32 rows x 64 j), P = exp(S) -> LDS ----
        const char* kbuf = lds + 32768 + cur * 8192;
#pragma unroll
        for (int jc = 0; jc < 4; jc++) {
            bs8 kf0 = *(const bs8*)(kbuf + (jc * 16 + l16) * 128 + ((quad ^ l7) << 4));
            bs8 kf1 = *(const bs8*)(kbuf + (jc * 16 + l16) * 128 + (((quad + 4) ^ l7) << 4));
#pragma unroll
            for (int sub = 0; sub < 2; sub++) {
                f32x4 z = (f32x4){0.f, 0.f, 0.f, 0.f};
                z = MFMA16(qa[sub][0], kf0, z);
                z = MFMA16(qa[sub][1], kf1, z);
#pragma unroll
                for (int reg = 0; reg < 4; reg++) {
                    int row = w * 32 + sub * 16 + quad * 4 + reg;
                    int j   = jc * 16 + l16;
                    bf16 h = __float2bfloat16(__expf(z[reg]));
                    *(short*)(lds + row * 128 +
                              ((((j >> 3) ^ (row & 7)) << 4)) + (j & 7) * 2) = *(short*)&h;
                }
            }
        }

        // ---- K stage write (pre-barrier; dbuf parity is race-free) ----
        if (jt < 63)
            *(uint4*)(lds + 32768 + nxt * 8192 + kw_off) = kreg;

        // Publish P + K(jt+1): LDS drain only; V loads stay in flight.
        asm volatile("s_waitcnt lgkmcnt(0)" ::: "memory");
        __builtin_amdgcn_s_barrier();
        __builtin_amdgcn_sched_barrier(0);

        // ---- PV: l += P.1, O += P.V  (P + V from LDS) ----
        const char* vbuf = lds + 49152 + cur * 32768;
        __builtin_amdgcn_s_setprio(1);
#pragma unroll
        for (int kc = 0; kc < 2; kc++) {
            bs8 pa[4];
#pragma unroll
            for (int sub = 0; sub < 4; sub++)
                pa[sub] = *(const bs8*)(lds + (iw * 64 + sub * 16 + l16) * 128 +
                                        (((kc * 4 + quad) ^ l7) << 4));
#pragma unroll
            for (int sub = 0; sub < 4; sub++)
                lacc[sub] = MFMA16(pa[sub], ones, lacc[sub]);
#pragma unroll
            for (int ct = 0; ct < 8; ct++) {
                bs8 vf = *(const bs8*)(vbuf + (cw * 128 + ct * 16 + l16) * 128 +
                                       (((kc * 4 + quad) ^ l7) << 4));
#pragma unroll
                for (int sub = 0; sub < 4; sub++)
                    oacc[sub][ct] = MFMA16(pa[sub], vf, oacc[sub][ct]);
            }
        }
        __builtin_amdgcn_s_setprio(0);

        // ---- V stage write (post-PV; dbuf parity is race-free) ----
        if (jt < 63) {
            char* vd = lds + 49152 + nxt * 32768 + vw_row;
#pragma unroll
            for (int q = 0; q < 4; q++)
                *(uint4*)(vd + (((vhalf * 4 + q) ^ vch7) << 4)) = vreg[q];
        }
    }

    // ---- epilogue: out = gamma*O/l + x ----
    const float g = gamma[0];
#pragma unroll
    for (int sub = 0; sub < 4; sub++) {
        float inv0 = g / lacc[sub][0];
        float inv1 = g / lacc[sub][1];
        float inv2 = g / lacc[sub][2];
        float inv3 = g / lacc[sub][3];
#pragma unroll
        for (int ct = 0; ct < 8; ct++) {
            int c = ch0 + cw * 128 + ct * 16 + l16;
            int n = i0 + iw * 64 + sub * 16 + quad * 4;
            size_t idx = ((size_t)b * C_ + c) * N_ + n;
            float4 xv = *(const float4*)(x + idx);
            float4 o;
            o.x = oacc[sub][ct][0] * inv0 + xv.x;
            o.y = oacc[sub][ct][1] * inv1 + xv.y;
            o.z = oacc[sub][ct][2] * inv2 + xv.z;
            o.w = oacc[sub][ct][3] * inv3 + xv.w;
            *(float4*)(out + idx) = o;
        }
    }
}

// ---------------------------------------------------------------------------
extern "C" void kernel_launch(void* const* d_in, const int* in_sizes, int n_in,
                              void* d_out, int out_size, void* d_ws, size_t ws_size,
                              hipStream_t stream)
{
    const float* x     = (const float*)d_in[0];
    const float* Wq    = (const float*)d_in[1];
    const float* bq    = (const float*)d_in[2];
    const float* Wk    = (const float*)d_in[3];
    const float* bk    = (const float*)d_in[4];
    const float* Wv    = (const float*)d_in[5];
    const float* bv    = (const float*)d_in[6];
    const float* gamma = (const float*)d_in[7];
    float* out = (float*)d_out;

    dim3 blk(256);
    dim3 blk512(512);

    const size_t szQ  = (size_t)B_ * N_ * CQ_ * sizeof(bf16);  //  4,194,304
    const size_t szVt = (size_t)B_ * N_ * C_ * sizeof(bf16);   // 33,554,432
    const size_t szWq = (size_t)CQ_ * C_ * sizeof(bf16);       //     65,536
    const size_t szWv = (size_t)C_ * C_ * sizeof(bf16);        //    524,288
    const size_t need_full = 2 * szQ + szVt + 2 * szWq + szWv; // ~42.6 MB

    if (ws_size >= need_full) {
        char* ws = (char*)d_ws;
        bf16* Q   = (bf16*)ws;
        bf16* K   = (bf16*)(ws + szQ);
        bf16* Vt  = (bf16*)(ws + 2 * szQ);
        bf16* Wqb = (bf16*)(ws + 2 * szQ + szVt);
        bf16* Wkb = (bf16*)((char*)Wqb + szWq);
        bf16* Wvb = (bf16*)((char*)Wkb + szWq);

        cast_weights<<<dim3(320), blk, 0, stream>>>(Wq, Wk, Wv, Wqb, Wkb, Wvb);
        proj_fused<<<dim3(64, B_), blk, 0, stream>>>(
            x, Wqb, Wkb, Wvb, bq, bk, bv, Q, K, Vt);
        attn_fused<<<dim3(B_, 16, 2), blk512, 0, stream>>>(Q, K, Vt, x, gamma, out);
    } else {
        // Per-batch chunked fallback
        const size_t qb = (size_t)N_ * CQ_ * sizeof(bf16);
        char* ws = (char*)d_ws;
        bf16* Wqb = (bf16*)ws;
        bf16* Wkb = (bf16*)(ws + szWq);
        bf16* Wvb = (bf16*)(ws + 2 * szWq);
        bf16* Q   = (bf16*)(ws + 2 * szWq + szWv);
        bf16* K   = (bf16*)((char*)Q + qb);
        bf16* Vt  = (bf16*)((char*)K + qb);

        cast_weights<<<dim3(320), blk, 0, stream>>>(Wq, Wk, Wv, Wqb, Wkb, Wvb);

        for (int b = 0; b < B_; b++) {
            const float* xb = x + (size_t)b * C_ * N_;
            float*       ob = out + (size_t)b * C_ * N_;
            proj_fused<<<dim3(64, 1), blk, 0, stream>>>(
                xb, Wqb, Wkb, Wvb, bq, bk, bv, Q, K, Vt);
            attn_fused<<<dim3(1, 16, 2), blk512, 0, stream>>>(Q, K, Vt, xb, gamma, ob);
        }
    }
}